// Round 13
// baseline (228.794 us; speedup 1.0000x reference)
//
#include <hip/hip_runtime.h>

typedef unsigned short u16;
typedef __bf16 bf16x8 __attribute__((ext_vector_type(8)));
typedef float f32x4 __attribute__((ext_vector_type(4)));
typedef unsigned int u32x2 __attribute__((ext_vector_type(2)));

__device__ __forceinline__ u16 f2bf(float f) {
  unsigned int u = __builtin_bit_cast(unsigned int, f);
  u += 0x7fffu + ((u >> 16) & 1u);
  return (u16)(u >> 16);
}
__device__ __forceinline__ float bf2f(u16 h) {
  unsigned int u = ((unsigned int)h) << 16;
  return __builtin_bit_cast(float, u);
}

// ---------------------------------------------------------------------------
// k_xcvt: X fp32 -> bf16, pure stream (fillBuffer-shaped: grid-stride, no
// barriers, no LDS). This kernel IS the read-bandwidth diagnostic.
// ---------------------------------------------------------------------------
__global__ __launch_bounds__(256) void k_xcvt(const f32x4* __restrict__ X4,
                                              u32x2* __restrict__ O2, long n4) {
  long i0 = (long)blockIdx.x * 256 + threadIdx.x;
  long stride = (long)gridDim.x * 256;
  for (long i = i0; i < n4; i += stride) {
    f32x4 v = __builtin_nontemporal_load(&X4[i]);
    u32x2 pk;
    pk.x = (unsigned int)f2bf(v[0]) | ((unsigned int)f2bf(v[1]) << 16);
    pk.y = (unsigned int)f2bf(v[2]) | ((unsigned int)f2bf(v[3]) << 16);
    __builtin_nontemporal_store(pk, &O2[i]);
  }
}

// ---------------------------------------------------------------------------
// k_prep: fp32 weights -> bf16 MFMA B-fragment order.
// Fragment (ks, nt, lane): 8 elems W[ks*32 + (lane>>4)*8 + j][nt*16 + (lane&15)]
// at dst[((ks*16+nt)*64 + lane)*8 + j].
// ---------------------------------------------------------------------------
__global__ __launch_bounds__(256) void k_prep(
    const float* __restrict__ W1, const float* __restrict__ W2,
    const float* __restrict__ R1, const float* __restrict__ R2, const float* __restrict__ R3,
    u16* __restrict__ W1s, u16* __restrict__ W2s,
    u16* __restrict__ R1s, u16* __restrict__ R2s, u16* __restrict__ R3s) {
  int t = blockIdx.x * 256 + threadIdx.x;
  const float* src; u16* dst; int lt;
  if (t < 12288) { src = W1; dst = W1s; lt = t; }
  else {
    int u = t - 12288;
    int m = u >> 13;
    lt = u & 8191;
    if (m == 0)      { src = W2; dst = W2s; }
    else if (m == 1) { src = R1; dst = R1s; }
    else if (m == 2) { src = R2; dst = R2s; }
    else if (m == 3) { src = R3; dst = R3s; }
    else return;
  }
  int lane = lt & 63;
  int nt = (lt >> 6) & 15;
  int ks = lt >> 10;
  int col = nt * 16 + (lane & 15);
  int kb = ks * 32 + (lane >> 4) * 8;
  union { u16 u[8]; uint4 v; } o;
#pragma unroll
  for (int j = 0; j < 8; ++j) o.u[j] = f2bf(src[(size_t)(kb + j) * 256 + col]);
  *(uint4*)(dst + (size_t)lt * 8) = o.v;
}

// ---------------------------------------------------------------------------
// CSR build: histogram -> 3-stage multi-block exclusive scan -> scatter.
// ---------------------------------------------------------------------------
__global__ __launch_bounds__(256) void k_hist(const int* __restrict__ cells,
                                              int* __restrict__ counts, int E) {
  int e = blockIdx.x * 256 + threadIdx.x;
  if (e < E) atomicAdd(&counts[cells[e]], 1);
}

__global__ __launch_bounds__(256) void k_scan1(const int* __restrict__ counts,
                                               int* __restrict__ offs,
                                               int* __restrict__ bsum, int M) {
  __shared__ int ws[4];
  int tid = threadIdx.x, lane = tid & 63, wid = tid >> 6;
  int i = blockIdx.x * 256 + tid;
  int v = (i < M) ? counts[i] : 0;
  int x = v;
#pragma unroll
  for (int s = 1; s < 64; s <<= 1) { int y = __shfl_up(x, s); if (lane >= s) x += y; }
  if (lane == 63) ws[wid] = x;
  __syncthreads();
  int pre = 0;
#pragma unroll
  for (int w = 0; w < 4; ++w) if (w < wid) pre += ws[w];
  if (i < M) offs[i] = pre + x - v;
  if (tid == 255) bsum[blockIdx.x] = pre + x;
}

__global__ __launch_bounds__(256) void k_scan2(int* __restrict__ bsum, int nb) {
  __shared__ int ws[4];
  int tid = threadIdx.x, lane = tid & 63, wid = tid >> 6;
  int v = (tid < nb) ? bsum[tid] : 0;
  int x = v;
#pragma unroll
  for (int s = 1; s < 64; s <<= 1) { int y = __shfl_up(x, s); if (lane >= s) x += y; }
  if (lane == 63) ws[wid] = x;
  __syncthreads();
  int pre = 0;
#pragma unroll
  for (int w = 0; w < 4; ++w) if (w < wid) pre += ws[w];
  if (tid < nb) bsum[tid] = pre + x - v;
}

__global__ __launch_bounds__(256) void k_scan3(int* __restrict__ offs,
                                               const int* __restrict__ bsum,
                                               int* __restrict__ cursor, int M, int E) {
  int i = blockIdx.x * 256 + threadIdx.x;
  if (i < M) { int o = offs[i] + bsum[blockIdx.x]; offs[i] = o; cursor[i] = o; }
  if (i == M) offs[M] = E;
}

__global__ __launch_bounds__(256) void k_scatter(const int* __restrict__ cells,
                                                 const int* __restrict__ nodes,
                                                 int* __restrict__ cursor,
                                                 int* __restrict__ sorted, int E) {
  int e = blockIdx.x * 256 + threadIdx.x;
  if (e < E) {
    int c = cells[e];
    int p = atomicAdd(&cursor[c], 1);
    sorted[p] = nodes[e];
  }
}

// ---------------------------------------------------------------------------
// k_phi_big: H = relu(relu(Xb@W1+b1)@W2+b2), Xb bf16. 1024-thread blocks
// (16 co-resident waves), 128-row tile, wave w owns n-tile w. 64KB LDS buf
// time-shared X/h1/h2 (XOR swizzle ^((row&15)<<3) u16 units, 0 conflicts).
// Staging is plain uint4 copies of pre-converted bf16 (half the read bytes).
// ---------------------------------------------------------------------------
__global__ __launch_bounds__(1024) void k_phi_big(
    const u16* __restrict__ Xb,
    const u16* __restrict__ W1s, const float* __restrict__ b1,
    const u16* __restrict__ W2s, const float* __restrict__ b2,
    u16* __restrict__ H, int N) {
  __shared__ __align__(16) u16 buf[128 * 256];
  const int tid = threadIdx.x, lane = tid & 63, wid = tid >> 6;  // wid 0..15 = nt
  const int g = lane >> 4, r16 = lane & 15;
  const int swz = r16 << 3;
  const int rbase = blockIdx.x * 128;

  const u16* w1p = W1s + (size_t)wid * 512 + lane * 8;  // + ks*8192
  const u16* w2p = W2s + (size_t)wid * 512 + lane * 8;

  const float bias1 = b1[wid * 16 + r16];
  const float bias2 = b2[wid * 16 + r16];

  // ---- stage phase 0: Xb cols [0,256) ----
  {
    uint4 xr[4];
#pragma unroll
    for (int it = 0; it < 4; ++it) {
      int u = it * 1024 + tid;
      int row = u >> 5, k8 = u & 31;
      int crow = rbase + row; crow = crow < N ? crow : N - 1;
      xr[it] = *(const uint4*)(Xb + (size_t)crow * 384 + k8 * 8);
    }
#pragma unroll
    for (int it = 0; it < 4; ++it) {
      int u = it * 1024 + tid;
      int row = u >> 5, k8 = u & 31;
      *(uint4*)(buf + row * 256 + ((k8 * 8) ^ ((row & 15) << 3))) = xr[it];
    }
  }
  __syncthreads();

  f32x4 acc[8];
#pragma unroll
  for (int m = 0; m < 8; ++m) acc[m] = (f32x4){0.f, 0.f, 0.f, 0.f};

  // ---- layer 1, K phase 0 (ks 0..7) ----
#pragma unroll 2
  for (int ks = 0; ks < 8; ++ks) {
    bf16x8 bfr = *(const bf16x8*)(w1p + (size_t)ks * 8192);
    const u16* bp = buf + ((ks * 32 + g * 8) ^ swz);
#pragma unroll
    for (int m = 0; m < 8; ++m) {
      bf16x8 af = *(const bf16x8*)(bp + (m * 16 + r16) * 256);
      acc[m] = __builtin_amdgcn_mfma_f32_16x16x32_bf16(af, bfr, acc[m], 0, 0, 0);
    }
  }
  __syncthreads();  // done reading phase-0 A

  // ---- stage phase 1: Xb cols [256,384) into buf u16-cols [0,128) ----
  {
    uint4 xr[2];
#pragma unroll
    for (int it = 0; it < 2; ++it) {
      int u = it * 1024 + tid;
      int row = u >> 4, k8 = u & 15;
      int crow = rbase + row; crow = crow < N ? crow : N - 1;
      xr[it] = *(const uint4*)(Xb + (size_t)crow * 384 + 256 + k8 * 8);
    }
#pragma unroll
    for (int it = 0; it < 2; ++it) {
      int u = it * 1024 + tid;
      int row = u >> 4, k8 = u & 15;
      *(uint4*)(buf + row * 256 + ((k8 * 8) ^ ((row & 15) << 3))) = xr[it];
    }
  }
  __syncthreads();

  // ---- layer 1, K phase 1 (ks 8..11) ----
#pragma unroll
  for (int ksl = 0; ksl < 4; ++ksl) {
    bf16x8 bfr = *(const bf16x8*)(w1p + (size_t)(8 + ksl) * 8192);
    const u16* bp = buf + ((ksl * 32 + g * 8) ^ swz);
#pragma unroll
    for (int m = 0; m < 8; ++m) {
      bf16x8 af = *(const bf16x8*)(bp + (m * 16 + r16) * 256);
      acc[m] = __builtin_amdgcn_mfma_f32_16x16x32_bf16(af, bfr, acc[m], 0, 0, 0);
    }
  }
  __syncthreads();  // done reading phase-1 A; buf free for h1

  // ---- h1 = relu(acc + b1) -> buf ----
#pragma unroll
  for (int m = 0; m < 8; ++m)
#pragma unroll
    for (int rr = 0; rr < 4; ++rr) {
      int row = m * 16 + g * 4 + rr;
      int col = wid * 16 + r16;
      float v = fmaxf(acc[m][rr] + bias1, 0.f);
      buf[row * 256 + (col ^ ((row & 15) << 3))] = f2bf(v);
    }
  __syncthreads();

  // ---- layer 2 (reuse acc) ----
#pragma unroll
  for (int m = 0; m < 8; ++m) acc[m] = (f32x4){0.f, 0.f, 0.f, 0.f};
#pragma unroll 2
  for (int ks = 0; ks < 8; ++ks) {
    bf16x8 bfr = *(const bf16x8*)(w2p + (size_t)ks * 8192);
    const u16* bp = buf + ((ks * 32 + g * 8) ^ swz);
#pragma unroll
    for (int m = 0; m < 8; ++m) {
      bf16x8 af = *(const bf16x8*)(bp + (m * 16 + r16) * 256);
      acc[m] = __builtin_amdgcn_mfma_f32_16x16x32_bf16(af, bfr, acc[m], 0, 0, 0);
    }
  }
  __syncthreads();  // done reading h1

  // ---- h2 = relu(acc + b2) -> buf ----
#pragma unroll
  for (int m = 0; m < 8; ++m)
#pragma unroll
    for (int rr = 0; rr < 4; ++rr) {
      int row = m * 16 + g * 4 + rr;
      int col = wid * 16 + r16;
      float v = fmaxf(acc[m][rr] + bias2, 0.f);
      buf[row * 256 + (col ^ ((row & 15) << 3))] = f2bf(v);
    }
  __syncthreads();

  // ---- coalesced copy out ----
#pragma unroll
  for (int it = 0; it < 4; ++it) {
    int u = it * 1024 + tid;
    int row = u >> 5, k8 = u & 31;
    uint4 d = *(const uint4*)(buf + row * 256 + ((k8 * 8) ^ ((row & 15) << 3)));
    int grow = rbase + row;
    if (grow < N) *(uint4*)(H + (size_t)grow * 256 + k8 * 8) = d;
  }
}

// ---------------------------------------------------------------------------
// k_cellsum: one wave per cell; pre-resolve sorted indices, __shfl-broadcast,
// 8-wide batched H-row loads (8 rows in flight per wave).
// ---------------------------------------------------------------------------
__global__ __launch_bounds__(256) void k_cellsum(
    const u16* __restrict__ H, const int* __restrict__ sorted,
    const int* __restrict__ offs, u16* __restrict__ CS, int M) {
  const int lane = threadIdx.x & 63, wid = threadIdx.x >> 6;
  int c = blockIdx.x * 4 + wid;
  if (c >= M) return;
  int s = offs[c], e = offs[c + 1];
  float a0 = 0.f, a1 = 0.f, a2 = 0.f, a3 = 0.f;
  for (int base = s; base < e; base += 64) {
    int cnt = e - base; if (cnt > 64) cnt = 64;
    int idx = sorted[base + (lane < cnt ? lane : 0)];
    int j = 0;
    for (; j + 8 <= cnt; j += 8) {
      ushort4 h[8];
#pragma unroll
      for (int q = 0; q < 8; ++q) {
        int nd = __shfl(idx, j + q);
        h[q] = *(const ushort4*)(H + (size_t)nd * 256 + lane * 4);
      }
#pragma unroll
      for (int q = 0; q < 8; ++q) {
        a0 += bf2f(h[q].x); a1 += bf2f(h[q].y);
        a2 += bf2f(h[q].z); a3 += bf2f(h[q].w);
      }
    }
    if (j + 4 <= cnt) {
      ushort4 h[4];
#pragma unroll
      for (int q = 0; q < 4; ++q) {
        int nd = __shfl(idx, j + q);
        h[q] = *(const ushort4*)(H + (size_t)nd * 256 + lane * 4);
      }
#pragma unroll
      for (int q = 0; q < 4; ++q) {
        a0 += bf2f(h[q].x); a1 += bf2f(h[q].y);
        a2 += bf2f(h[q].z); a3 += bf2f(h[q].w);
      }
      j += 4;
    }
    for (; j < cnt; ++j) {
      int nd = __shfl(idx, j);
      ushort4 h = *(const ushort4*)(H + (size_t)nd * 256 + lane * 4);
      a0 += bf2f(h.x); a1 += bf2f(h.y); a2 += bf2f(h.z); a3 += bf2f(h.w);
    }
  }
  ushort4 o;
  o.x = f2bf(a0); o.y = f2bf(a1); o.z = f2bf(a2); o.w = f2bf(a3);
  *(ushort4*)(CS + (size_t)c * 256 + lane * 4) = o;
}

// ---------------------------------------------------------------------------
// k_rho_big: OUT = relu(relu(CS@R1+c1)@R2+c2)@R3+c3. 1024-thread blocks,
// 128-row tiles, wave w = n-tile w, 3 fused layers, 64KB LDS time-shared.
// ---------------------------------------------------------------------------
__global__ __launch_bounds__(1024) void k_rho_big(
    const u16* __restrict__ CS,
    const u16* __restrict__ R1s, const float* __restrict__ c1,
    const u16* __restrict__ R2s, const float* __restrict__ c2,
    const u16* __restrict__ R3s, const float* __restrict__ c3,
    float* __restrict__ OUT, int M) {
  __shared__ __align__(16) u16 buf[128 * 256];
  const int tid = threadIdx.x, lane = tid & 63, wid = tid >> 6;
  const int g = lane >> 4, r16 = lane & 15;
  const int swz = r16 << 3;
  const int rbase = blockIdx.x * 128;

  const u16* w1p = R1s + (size_t)wid * 512 + lane * 8;
  const u16* w2p = R2s + (size_t)wid * 512 + lane * 8;
  const u16* w3p = R3s + (size_t)wid * 512 + lane * 8;

  const float bias1 = c1[wid * 16 + r16];
  const float bias2 = c2[wid * 16 + r16];
  const float bias3 = c3[wid * 16 + r16];

  // ---- stage CS tile (bf16 already) ----
  {
    uint4 xr[4];
#pragma unroll
    for (int it = 0; it < 4; ++it) {
      int u = it * 1024 + tid;
      int row = u >> 5, k8 = u & 31;
      int crow = rbase + row; crow = crow < M ? crow : M - 1;
      xr[it] = *(const uint4*)(CS + (size_t)crow * 256 + k8 * 8);
    }
#pragma unroll
    for (int it = 0; it < 4; ++it) {
      int u = it * 1024 + tid;
      int row = u >> 5, k8 = u & 31;
      *(uint4*)(buf + row * 256 + ((k8 * 8) ^ ((row & 15) << 3))) = xr[it];
    }
  }
  __syncthreads();

  f32x4 acc[8];

  // ---- layer 1 ----
#pragma unroll
  for (int m = 0; m < 8; ++m) acc[m] = (f32x4){0.f, 0.f, 0.f, 0.f};
#pragma unroll 2
  for (int ks = 0; ks < 8; ++ks) {
    bf16x8 bfr = *(const bf16x8*)(w1p + (size_t)ks * 8192);
    const u16* bp = buf + ((ks * 32 + g * 8) ^ swz);
#pragma unroll
    for (int m = 0; m < 8; ++m) {
      bf16x8 af = *(const bf16x8*)(bp + (m * 16 + r16) * 256);
      acc[m] = __builtin_amdgcn_mfma_f32_16x16x32_bf16(af, bfr, acc[m], 0, 0, 0);
    }
  }
  __syncthreads();  // done reading CS tile

  // ---- h1 -> buf ----
#pragma unroll
  for (int m = 0; m < 8; ++m)
#pragma unroll
    for (int rr = 0; rr < 4; ++rr) {
      int row = m * 16 + g * 4 + rr;
      int col = wid * 16 + r16;
      float v = fmaxf(acc[m][rr] + bias1, 0.f);
      buf[row * 256 + (col ^ ((row & 15) << 3))] = f2bf(v);
    }
  __syncthreads();

  // ---- layer 2 ----
#pragma unroll
  for (int m = 0; m < 8; ++m) acc[m] = (f32x4){0.f, 0.f, 0.f, 0.f};
#pragma unroll 2
  for (int ks = 0; ks < 8; ++ks) {
    bf16x8 bfr = *(const bf16x8*)(w2p + (size_t)ks * 8192);
    const u16* bp = buf + ((ks * 32 + g * 8) ^ swz);
#pragma unroll
    for (int m = 0; m < 8; ++m) {
      bf16x8 af = *(const bf16x8*)(bp + (m * 16 + r16) * 256);
      acc[m] = __builtin_amdgcn_mfma_f32_16x16x32_bf16(af, bfr, acc[m], 0, 0, 0);
    }
  }
  __syncthreads();  // done reading h1

  // ---- h2 -> buf ----
#pragma unroll
  for (int m = 0; m < 8; ++m)
#pragma unroll
    for (int rr = 0; rr < 4; ++rr) {
      int row = m * 16 + g * 4 + rr;
      int col = wid * 16 + r16;
      float v = fmaxf(acc[m][rr] + bias2, 0.f);
      buf[row * 256 + (col ^ ((row & 15) << 3))] = f2bf(v);
    }
  __syncthreads();

  // ---- layer 3 (no relu), direct fp32 stores ----
#pragma unroll
  for (int m = 0; m < 8; ++m) acc[m] = (f32x4){0.f, 0.f, 0.f, 0.f};
#pragma unroll 2
  for (int ks = 0; ks < 8; ++ks) {
    bf16x8 bfr = *(const bf16x8*)(w3p + (size_t)ks * 8192);
    const u16* bp = buf + ((ks * 32 + g * 8) ^ swz);
#pragma unroll
    for (int m = 0; m < 8; ++m) {
      bf16x8 af = *(const bf16x8*)(bp + (m * 16 + r16) * 256);
      acc[m] = __builtin_amdgcn_mfma_f32_16x16x32_bf16(af, bfr, acc[m], 0, 0, 0);
    }
  }
#pragma unroll
  for (int m = 0; m < 8; ++m)
#pragma unroll
    for (int rr = 0; rr < 4; ++rr) {
      int grow = rbase + m * 16 + g * 4 + rr;
      if (grow < M)
        OUT[(size_t)grow * 256 + wid * 16 + r16] = acc[m][rr] + bias3;
    }
}

// ---------------------------------------------------------------------------
extern "C" void kernel_launch(void* const* d_in, const int* in_sizes, int n_in,
                              void* d_out, int out_size, void* d_ws, size_t ws_size,
                              hipStream_t stream) {
  const float* X    = (const float*)d_in[0];
  const int* nodes  = (const int*)d_in[1];
  const int* cells  = (const int*)d_in[2];
  const float* W1   = (const float*)d_in[4];
  const float* b1   = (const float*)d_in[5];
  const float* W2   = (const float*)d_in[6];
  const float* b2   = (const float*)d_in[7];
  const float* R1   = (const float*)d_in[8];
  const float* c1   = (const float*)d_in[9];
  const float* R2   = (const float*)d_in[10];
  const float* c2   = (const float*)d_in[11];
  const float* R3   = (const float*)d_in[12];
  const float* c3   = (const float*)d_in[13];
  float* OUT = (float*)d_out;

  const int N = in_sizes[0] / 384;   // 100000
  const int E = in_sizes[1];         // 400000
  const int M = out_size / 256;      // 50000

  char* ws = (char*)d_ws;
  size_t off = 0;
  auto alloc = [&](size_t b) { size_t o = off; off += (b + 255) & ~(size_t)255; return o; };
  u16* W1s    = (u16*)(ws + alloc((size_t)12 * 16 * 64 * 8 * 2));
  u16* W2s    = (u16*)(ws + alloc((size_t)8 * 16 * 64 * 8 * 2));
  u16* R1s    = (u16*)(ws + alloc((size_t)8 * 16 * 64 * 8 * 2));
  u16* R2s    = (u16*)(ws + alloc((size_t)8 * 16 * 64 * 8 * 2));
  u16* R3s    = (u16*)(ws + alloc((size_t)8 * 16 * 64 * 8 * 2));
  u16* Xb     = (u16*)(ws + alloc((size_t)N * 384 * 2));
  u16* H      = (u16*)(ws + alloc((size_t)N * 256 * 2));
  u16* CS     = (u16*)(ws + alloc((size_t)M * 256 * 2));
  int* counts = (int*)(ws + alloc((size_t)M * 4));
  int* offs   = (int*)(ws + alloc((size_t)(M + 1) * 4));
  int* cursor = (int*)(ws + alloc((size_t)M * 4));
  int* sorted = (int*)(ws + alloc((size_t)E * 4));
  int* bsum   = (int*)(ws + alloc((size_t)256 * 4));

  const int NB = (M + 255) / 256;
  const long n4 = (long)N * 384 / 4;  // 9.6M f32x4

  hipMemsetAsync(counts, 0, (size_t)M * 4, stream);
  k_xcvt<<<4096, 256, 0, stream>>>((const f32x4*)X, (u32x2*)Xb, n4);
  k_prep<<<176, 256, 0, stream>>>(W1, W2, R1, R2, R3, W1s, W2s, R1s, R2s, R3s);
  k_hist<<<(E + 255) / 256, 256, 0, stream>>>(cells, counts, E);
  k_scan1<<<NB, 256, 0, stream>>>(counts, offs, bsum, M);
  k_scan2<<<1, 256, 0, stream>>>(bsum, NB);
  k_scan3<<<(M + 256) / 256, 256, 0, stream>>>(offs, bsum, cursor, M, E);
  k_scatter<<<(E + 255) / 256, 256, 0, stream>>>(cells, nodes, cursor, sorted, E);
  k_phi_big<<<(N + 127) / 128, 1024, 0, stream>>>(Xb, W1s, b1, W2s, b2, H, N);
  k_cellsum<<<(M + 3) / 4, 256, 0, stream>>>(H, sorted, offs, CS, M);
  k_rho_big<<<(M + 127) / 128, 1024, 0, stream>>>(CS, R1s, c1, R2s, c2, R3s, c3, OUT, M);
}

// Round 15
// 200.190 us; speedup vs baseline: 1.1429x; 1.1429x over previous
//
#include <hip/hip_runtime.h>

typedef unsigned short u16;
typedef __bf16 bf16x8 __attribute__((ext_vector_type(8)));
typedef float f32x4 __attribute__((ext_vector_type(4)));
typedef unsigned int u32x4 __attribute__((ext_vector_type(4)));

__device__ __forceinline__ u16 f2bf(float f) {
  unsigned int u = __builtin_bit_cast(unsigned int, f);
  u += 0x7fffu + ((u >> 16) & 1u);
  return (u16)(u >> 16);
}
__device__ __forceinline__ float bf2f(u16 h) {
  unsigned int u = ((unsigned int)h) << 16;
  return __builtin_bit_cast(float, u);
}

// ---------------------------------------------------------------------------
// k_preph: merged {weight prep (blocks 0..175)} + {cell histogram (blocks
// 176..)} — independent work, one launch, overlapped execution.
// Weight fragment (ks, nt, lane): 8 elems W[ks*32+(lane>>4)*8+j][nt*16+(lane&15)]
// at dst[((ks*16+nt)*64 + lane)*8 + j].
// ---------------------------------------------------------------------------
__global__ __launch_bounds__(256) void k_preph(
    const float* __restrict__ W1, const float* __restrict__ W2,
    const float* __restrict__ R1, const float* __restrict__ R2, const float* __restrict__ R3,
    u16* __restrict__ W1s, u16* __restrict__ W2s,
    u16* __restrict__ R1s, u16* __restrict__ R2s, u16* __restrict__ R3s,
    const int* __restrict__ cells, int* __restrict__ counts, int E) {
  if (blockIdx.x >= 176) {
    int e = (blockIdx.x - 176) * 256 + threadIdx.x;
    if (e < E) atomicAdd(&counts[cells[e]], 1);
    return;
  }
  int t = blockIdx.x * 256 + threadIdx.x;
  const float* src; u16* dst; int lt;
  if (t < 12288) { src = W1; dst = W1s; lt = t; }
  else {
    int u = t - 12288;
    int m = u >> 13;
    lt = u & 8191;
    if (m == 0)      { src = W2; dst = W2s; }
    else if (m == 1) { src = R1; dst = R1s; }
    else if (m == 2) { src = R2; dst = R2s; }
    else if (m == 3) { src = R3; dst = R3s; }
    else return;
  }
  int lane = lt & 63;
  int nt = (lt >> 6) & 15;
  int ks = lt >> 10;
  int col = nt * 16 + (lane & 15);
  int kb = ks * 32 + (lane >> 4) * 8;
  union { u16 u[8]; uint4 v; } o;
#pragma unroll
  for (int j = 0; j < 8; ++j) o.u[j] = f2bf(src[(size_t)(kb + j) * 256 + col]);
  *(uint4*)(dst + (size_t)lt * 8) = o.v;
}

// ---------------------------------------------------------------------------
// CSR build: 3-stage multi-block exclusive scan -> scatter.
// ---------------------------------------------------------------------------
__global__ __launch_bounds__(256) void k_scan1(const int* __restrict__ counts,
                                               int* __restrict__ offs,
                                               int* __restrict__ bsum, int M) {
  __shared__ int ws[4];
  int tid = threadIdx.x, lane = tid & 63, wid = tid >> 6;
  int i = blockIdx.x * 256 + tid;
  int v = (i < M) ? counts[i] : 0;
  int x = v;
#pragma unroll
  for (int s = 1; s < 64; s <<= 1) { int y = __shfl_up(x, s); if (lane >= s) x += y; }
  if (lane == 63) ws[wid] = x;
  __syncthreads();
  int pre = 0;
#pragma unroll
  for (int w = 0; w < 4; ++w) if (w < wid) pre += ws[w];
  if (i < M) offs[i] = pre + x - v;
  if (tid == 255) bsum[blockIdx.x] = pre + x;
}

__global__ __launch_bounds__(256) void k_scan2(int* __restrict__ bsum, int nb) {
  __shared__ int ws[4];
  int tid = threadIdx.x, lane = tid & 63, wid = tid >> 6;
  int v = (tid < nb) ? bsum[tid] : 0;
  int x = v;
#pragma unroll
  for (int s = 1; s < 64; s <<= 1) { int y = __shfl_up(x, s); if (lane >= s) x += y; }
  if (lane == 63) ws[wid] = x;
  __syncthreads();
  int pre = 0;
#pragma unroll
  for (int w = 0; w < 4; ++w) if (w < wid) pre += ws[w];
  if (tid < nb) bsum[tid] = pre + x - v;
}

__global__ __launch_bounds__(256) void k_scan3(int* __restrict__ offs,
                                               const int* __restrict__ bsum,
                                               int* __restrict__ cursor, int M, int E) {
  int i = blockIdx.x * 256 + threadIdx.x;
  if (i < M) { int o = offs[i] + bsum[blockIdx.x]; offs[i] = o; cursor[i] = o; }
  if (i == M) offs[M] = E;
}

__global__ __launch_bounds__(256) void k_scatter(const int* __restrict__ cells,
                                                 const int* __restrict__ nodes,
                                                 int* __restrict__ cursor,
                                                 int* __restrict__ sorted, int E) {
  int e = blockIdx.x * 256 + threadIdx.x;
  if (e < E) {
    int c = cells[e];
    int p = atomicAdd(&cursor[c], 1);
    sorted[p] = nodes[e];
  }
}

// ---------------------------------------------------------------------------
// k_phi_big: H = relu(relu(X@W1+b1)@W2+b2). 1024-THREAD BLOCKS (16 waves
// co-resident, 4/SIMD). 128-row tile; wave w owns n-tile w: acc[8] f32x4.
// 64KB LDS buf time-shared X/h1/h2 (XOR swizzle ^((row&15)<<3) u16 units,
// 0 bank conflicts). ROUND-11 EXACT (best measured config: 107us).
// ---------------------------------------------------------------------------
__global__ __launch_bounds__(1024) void k_phi_big(
    const float* __restrict__ X,
    const u16* __restrict__ W1s, const float* __restrict__ b1,
    const u16* __restrict__ W2s, const float* __restrict__ b2,
    u16* __restrict__ H, int N) {
  __shared__ __align__(16) u16 buf[128 * 256];
  const int tid = threadIdx.x, lane = tid & 63, wid = tid >> 6;  // wid 0..15 = nt
  const int g = lane >> 4, r16 = lane & 15;
  const int swz = r16 << 3;
  const int rbase = blockIdx.x * 128;

  const u16* w1p = W1s + (size_t)wid * 512 + lane * 8;  // + ks*8192
  const u16* w2p = W2s + (size_t)wid * 512 + lane * 8;

  const float bias1 = b1[wid * 16 + r16];
  const float bias2 = b2[wid * 16 + r16];

  // ---- stage phase 0: X cols [0,256) ----
  {
    f32x4 xr[8];
#pragma unroll
    for (int it = 0; it < 8; ++it) {
      int u = it * 1024 + tid;
      int row = u >> 6, c4 = u & 63;
      int crow = rbase + row; crow = crow < N ? crow : N - 1;
      xr[it] = *(const f32x4*)(X + (size_t)crow * 384 + c4 * 4);
    }
#pragma unroll
    for (int it = 0; it < 8; ++it) {
      int u = it * 1024 + tid;
      int row = u >> 6, c4 = u & 63;
      uint2 pk;
      pk.x = (unsigned int)f2bf(xr[it][0]) | ((unsigned int)f2bf(xr[it][1]) << 16);
      pk.y = (unsigned int)f2bf(xr[it][2]) | ((unsigned int)f2bf(xr[it][3]) << 16);
      *(uint2*)(buf + row * 256 + ((c4 * 4) ^ ((row & 15) << 3))) = pk;
    }
  }
  __syncthreads();

  f32x4 acc[8];
#pragma unroll
  for (int m = 0; m < 8; ++m) acc[m] = (f32x4){0.f, 0.f, 0.f, 0.f};

  // ---- layer 1, K phase 0 (ks 0..7) ----
#pragma unroll 2
  for (int ks = 0; ks < 8; ++ks) {
    bf16x8 bfr = *(const bf16x8*)(w1p + (size_t)ks * 8192);
    const u16* bp = buf + ((ks * 32 + g * 8) ^ swz);
#pragma unroll
    for (int m = 0; m < 8; ++m) {
      bf16x8 af = *(const bf16x8*)(bp + (m * 16 + r16) * 256);
      acc[m] = __builtin_amdgcn_mfma_f32_16x16x32_bf16(af, bfr, acc[m], 0, 0, 0);
    }
  }
  __syncthreads();  // done reading phase-0 A

  // ---- stage phase 1: X cols [256,384) into buf u16-cols [0,128) ----
  {
    f32x4 xr[4];
#pragma unroll
    for (int it = 0; it < 4; ++it) {
      int u = it * 1024 + tid;
      int row = u >> 5, c4 = u & 31;
      int crow = rbase + row; crow = crow < N ? crow : N - 1;
      xr[it] = *(const f32x4*)(X + (size_t)crow * 384 + 256 + c4 * 4);
    }
#pragma unroll
    for (int it = 0; it < 4; ++it) {
      int u = it * 1024 + tid;
      int row = u >> 5, c4 = u & 31;
      uint2 pk;
      pk.x = (unsigned int)f2bf(xr[it][0]) | ((unsigned int)f2bf(xr[it][1]) << 16);
      pk.y = (unsigned int)f2bf(xr[it][2]) | ((unsigned int)f2bf(xr[it][3]) << 16);
      *(uint2*)(buf + row * 256 + ((c4 * 4) ^ ((row & 15) << 3))) = pk;
    }
  }
  __syncthreads();

  // ---- layer 1, K phase 1 (ks 8..11) ----
#pragma unroll
  for (int ksl = 0; ksl < 4; ++ksl) {
    bf16x8 bfr = *(const bf16x8*)(w1p + (size_t)(8 + ksl) * 8192);
    const u16* bp = buf + ((ksl * 32 + g * 8) ^ swz);
#pragma unroll
    for (int m = 0; m < 8; ++m) {
      bf16x8 af = *(const bf16x8*)(bp + (m * 16 + r16) * 256);
      acc[m] = __builtin_amdgcn_mfma_f32_16x16x32_bf16(af, bfr, acc[m], 0, 0, 0);
    }
  }
  __syncthreads();  // done reading phase-1 A; buf free for h1

  // ---- h1 = relu(acc + b1) -> buf ----
#pragma unroll
  for (int m = 0; m < 8; ++m)
#pragma unroll
    for (int rr = 0; rr < 4; ++rr) {
      int row = m * 16 + g * 4 + rr;
      int col = wid * 16 + r16;
      float v = fmaxf(acc[m][rr] + bias1, 0.f);
      buf[row * 256 + (col ^ ((row & 15) << 3))] = f2bf(v);
    }
  __syncthreads();

  // ---- layer 2 (reuse acc) ----
#pragma unroll
  for (int m = 0; m < 8; ++m) acc[m] = (f32x4){0.f, 0.f, 0.f, 0.f};
#pragma unroll 2
  for (int ks = 0; ks < 8; ++ks) {
    bf16x8 bfr = *(const bf16x8*)(w2p + (size_t)ks * 8192);
    const u16* bp = buf + ((ks * 32 + g * 8) ^ swz);
#pragma unroll
    for (int m = 0; m < 8; ++m) {
      bf16x8 af = *(const bf16x8*)(bp + (m * 16 + r16) * 256);
      acc[m] = __builtin_amdgcn_mfma_f32_16x16x32_bf16(af, bfr, acc[m], 0, 0, 0);
    }
  }
  __syncthreads();  // done reading h1

  // ---- h2 = relu(acc + b2) -> buf ----
#pragma unroll
  for (int m = 0; m < 8; ++m)
#pragma unroll
    for (int rr = 0; rr < 4; ++rr) {
      int row = m * 16 + g * 4 + rr;
      int col = wid * 16 + r16;
      float v = fmaxf(acc[m][rr] + bias2, 0.f);
      buf[row * 256 + (col ^ ((row & 15) << 3))] = f2bf(v);
    }
  __syncthreads();

  // ---- coalesced copy out ----
#pragma unroll
  for (int it = 0; it < 4; ++it) {
    int u = it * 1024 + tid;
    int row = u >> 5, k8 = u & 31;
    uint4 d = *(const uint4*)(buf + row * 256 + ((k8 * 8) ^ ((row & 15) << 3)));
    int grow = rbase + row;
    if (grow < N) *(uint4*)(H + (size_t)grow * 256 + k8 * 8) = d;
  }
}

// ---------------------------------------------------------------------------
// k_cellsum: one wave per cell; pre-resolve sorted indices, __shfl-broadcast,
// 8-wide batched H-row loads (8 rows in flight per wave).
// ---------------------------------------------------------------------------
__global__ __launch_bounds__(256) void k_cellsum(
    const u16* __restrict__ H, const int* __restrict__ sorted,
    const int* __restrict__ offs, u16* __restrict__ CS, int M) {
  const int lane = threadIdx.x & 63, wid = threadIdx.x >> 6;
  int c = blockIdx.x * 4 + wid;
  if (c >= M) return;
  int s = offs[c], e = offs[c + 1];
  float a0 = 0.f, a1 = 0.f, a2 = 0.f, a3 = 0.f;
  for (int base = s; base < e; base += 64) {
    int cnt = e - base; if (cnt > 64) cnt = 64;
    int idx = sorted[base + (lane < cnt ? lane : 0)];
    int j = 0;
    for (; j + 8 <= cnt; j += 8) {
      ushort4 h[8];
#pragma unroll
      for (int q = 0; q < 8; ++q) {
        int nd = __shfl(idx, j + q);
        h[q] = *(const ushort4*)(H + (size_t)nd * 256 + lane * 4);
      }
#pragma unroll
      for (int q = 0; q < 8; ++q) {
        a0 += bf2f(h[q].x); a1 += bf2f(h[q].y);
        a2 += bf2f(h[q].z); a3 += bf2f(h[q].w);
      }
    }
    if (j + 4 <= cnt) {
      ushort4 h[4];
#pragma unroll
      for (int q = 0; q < 4; ++q) {
        int nd = __shfl(idx, j + q);
        h[q] = *(const ushort4*)(H + (size_t)nd * 256 + lane * 4);
      }
#pragma unroll
      for (int q = 0; q < 4; ++q) {
        a0 += bf2f(h[q].x); a1 += bf2f(h[q].y);
        a2 += bf2f(h[q].z); a3 += bf2f(h[q].w);
      }
      j += 4;
    }
    for (; j < cnt; ++j) {
      int nd = __shfl(idx, j);
      ushort4 h = *(const ushort4*)(H + (size_t)nd * 256 + lane * 4);
      a0 += bf2f(h.x); a1 += bf2f(h.y); a2 += bf2f(h.z); a3 += bf2f(h.w);
    }
  }
  ushort4 o;
  o.x = f2bf(a0); o.y = f2bf(a1); o.z = f2bf(a2); o.w = f2bf(a3);
  *(ushort4*)(CS + (size_t)c * 256 + lane * 4) = o;
}

// ---------------------------------------------------------------------------
// k_rho_big: OUT = relu(relu(CS@R1+c1)@R2+c2)@R3+c3. 1024-thread blocks,
// 128-row tiles, wave w = n-tile w, 3 fused layers, 64KB LDS time-shared.
// NT loads for CS (read-once, ext-vector type) and NT stores for OUT.
// ---------------------------------------------------------------------------
__global__ __launch_bounds__(1024) void k_rho_big(
    const u16* __restrict__ CS,
    const u16* __restrict__ R1s, const float* __restrict__ c1,
    const u16* __restrict__ R2s, const float* __restrict__ c2,
    const u16* __restrict__ R3s, const float* __restrict__ c3,
    float* __restrict__ OUT, int M) {
  __shared__ __align__(16) u16 buf[128 * 256];
  const int tid = threadIdx.x, lane = tid & 63, wid = tid >> 6;
  const int g = lane >> 4, r16 = lane & 15;
  const int swz = r16 << 3;
  const int rbase = blockIdx.x * 128;

  const u16* w1p = R1s + (size_t)wid * 512 + lane * 8;
  const u16* w2p = R2s + (size_t)wid * 512 + lane * 8;
  const u16* w3p = R3s + (size_t)wid * 512 + lane * 8;

  const float bias1 = c1[wid * 16 + r16];
  const float bias2 = c2[wid * 16 + r16];
  const float bias3 = c3[wid * 16 + r16];

  // ---- stage CS tile (bf16 already), NT loads ----
  {
    u32x4 xr[4];
#pragma unroll
    for (int it = 0; it < 4; ++it) {
      int u = it * 1024 + tid;
      int row = u >> 5, k8 = u & 31;
      int crow = rbase + row; crow = crow < M ? crow : M - 1;
      xr[it] = __builtin_nontemporal_load((const u32x4*)(CS + (size_t)crow * 256 + k8 * 8));
    }
#pragma unroll
    for (int it = 0; it < 4; ++it) {
      int u = it * 1024 + tid;
      int row = u >> 5, k8 = u & 31;
      *(u32x4*)(buf + row * 256 + ((k8 * 8) ^ ((row & 15) << 3))) = xr[it];
    }
  }
  __syncthreads();

  f32x4 acc[8];

  // ---- layer 1 ----
#pragma unroll
  for (int m = 0; m < 8; ++m) acc[m] = (f32x4){0.f, 0.f, 0.f, 0.f};
#pragma unroll 2
  for (int ks = 0; ks < 8; ++ks) {
    bf16x8 bfr = *(const bf16x8*)(w1p + (size_t)ks * 8192);
    const u16* bp = buf + ((ks * 32 + g * 8) ^ swz);
#pragma unroll
    for (int m = 0; m < 8; ++m) {
      bf16x8 af = *(const bf16x8*)(bp + (m * 16 + r16) * 256);
      acc[m] = __builtin_amdgcn_mfma_f32_16x16x32_bf16(af, bfr, acc[m], 0, 0, 0);
    }
  }
  __syncthreads();  // done reading CS tile

  // ---- h1 -> buf ----
#pragma unroll
  for (int m = 0; m < 8; ++m)
#pragma unroll
    for (int rr = 0; rr < 4; ++rr) {
      int row = m * 16 + g * 4 + rr;
      int col = wid * 16 + r16;
      float v = fmaxf(acc[m][rr] + bias1, 0.f);
      buf[row * 256 + (col ^ ((row & 15) << 3))] = f2bf(v);
    }
  __syncthreads();

  // ---- layer 2 ----
#pragma unroll
  for (int m = 0; m < 8; ++m) acc[m] = (f32x4){0.f, 0.f, 0.f, 0.f};
#pragma unroll 2
  for (int ks = 0; ks < 8; ++ks) {
    bf16x8 bfr = *(const bf16x8*)(w2p + (size_t)ks * 8192);
    const u16* bp = buf + ((ks * 32 + g * 8) ^ swz);
#pragma unroll
    for (int m = 0; m < 8; ++m) {
      bf16x8 af = *(const bf16x8*)(bp + (m * 16 + r16) * 256);
      acc[m] = __builtin_amdgcn_mfma_f32_16x16x32_bf16(af, bfr, acc[m], 0, 0, 0);
    }
  }
  __syncthreads();  // done reading h1

  // ---- h2 -> buf ----
#pragma unroll
  for (int m = 0; m < 8; ++m)
#pragma unroll
    for (int rr = 0; rr < 4; ++rr) {
      int row = m * 16 + g * 4 + rr;
      int col = wid * 16 + r16;
      float v = fmaxf(acc[m][rr] + bias2, 0.f);
      buf[row * 256 + (col ^ ((row & 15) << 3))] = f2bf(v);
    }
  __syncthreads();

  // ---- layer 3 (no relu), NT fp32 stores ----
#pragma unroll
  for (int m = 0; m < 8; ++m) acc[m] = (f32x4){0.f, 0.f, 0.f, 0.f};
#pragma unroll 2
  for (int ks = 0; ks < 8; ++ks) {
    bf16x8 bfr = *(const bf16x8*)(w3p + (size_t)ks * 8192);
    const u16* bp = buf + ((ks * 32 + g * 8) ^ swz);
#pragma unroll
    for (int m = 0; m < 8; ++m) {
      bf16x8 af = *(const bf16x8*)(bp + (m * 16 + r16) * 256);
      acc[m] = __builtin_amdgcn_mfma_f32_16x16x32_bf16(af, bfr, acc[m], 0, 0, 0);
    }
  }
#pragma unroll
  for (int m = 0; m < 8; ++m)
#pragma unroll
    for (int rr = 0; rr < 4; ++rr) {
      int grow = rbase + m * 16 + g * 4 + rr;
      if (grow < M)
        __builtin_nontemporal_store(acc[m][rr] + bias3,
                                    OUT + (size_t)grow * 256 + wid * 16 + r16);
    }
}

// ---------------------------------------------------------------------------
extern "C" void kernel_launch(void* const* d_in, const int* in_sizes, int n_in,
                              void* d_out, int out_size, void* d_ws, size_t ws_size,
                              hipStream_t stream) {
  const float* X    = (const float*)d_in[0];
  const int* nodes  = (const int*)d_in[1];
  const int* cells  = (const int*)d_in[2];
  const float* W1   = (const float*)d_in[4];
  const float* b1   = (const float*)d_in[5];
  const float* W2   = (const float*)d_in[6];
  const float* b2   = (const float*)d_in[7];
  const float* R1   = (const float*)d_in[8];
  const float* c1   = (const float*)d_in[9];
  const float* R2   = (const float*)d_in[10];
  const float* c2   = (const float*)d_in[11];
  const float* R3   = (const float*)d_in[12];
  const float* c3   = (const float*)d_in[13];
  float* OUT = (float*)d_out;

  const int N = in_sizes[0] / 384;   // 100000
  const int E = in_sizes[1];         // 400000
  const int M = out_size / 256;      // 50000

  char* ws = (char*)d_ws;
  size_t off = 0;
  auto alloc = [&](size_t b) { size_t o = off; off += (b + 255) & ~(size_t)255; return o; };
  u16* W1s    = (u16*)(ws + alloc((size_t)12 * 16 * 64 * 8 * 2));
  u16* W2s    = (u16*)(ws + alloc((size_t)8 * 16 * 64 * 8 * 2));
  u16* R1s    = (u16*)(ws + alloc((size_t)8 * 16 * 64 * 8 * 2));
  u16* R2s    = (u16*)(ws + alloc((size_t)8 * 16 * 64 * 8 * 2));
  u16* R3s    = (u16*)(ws + alloc((size_t)8 * 16 * 64 * 8 * 2));
  u16* H      = (u16*)(ws + alloc((size_t)N * 256 * 2));
  u16* CS     = (u16*)(ws + alloc((size_t)M * 256 * 2));
  int* counts = (int*)(ws + alloc((size_t)M * 4));
  int* offs   = (int*)(ws + alloc((size_t)(M + 1) * 4));
  int* cursor = (int*)(ws + alloc((size_t)M * 4));
  int* sorted = (int*)(ws + alloc((size_t)E * 4));
  int* bsum   = (int*)(ws + alloc((size_t)256 * 4));

  const int NB = (M + 255) / 256;
  const int HB = (E + 255) / 256;

  hipMemsetAsync(counts, 0, (size_t)M * 4, stream);
  k_preph<<<176 + HB, 256, 0, stream>>>(W1, W2, R1, R2, R3, W1s, W2s, R1s, R2s, R3s,
                                        cells, counts, E);
  k_scan1<<<NB, 256, 0, stream>>>(counts, offs, bsum, M);
  k_scan2<<<1, 256, 0, stream>>>(bsum, NB);
  k_scan3<<<(M + 256) / 256, 256, 0, stream>>>(offs, bsum, cursor, M, E);
  k_scatter<<<(E + 255) / 256, 256, 0, stream>>>(cells, nodes, cursor, sorted, E);
  k_phi_big<<<(N + 127) / 128, 1024, 0, stream>>>(X, W1s, b1, W2s, b2, H, N);
  k_cellsum<<<(M + 3) / 4, 256, 0, stream>>>(H, sorted, offs, CS, M);
  k_rho_big<<<(M + 127) / 128, 1024, 0, stream>>>(CS, R1s, c1, R2s, c2, R3s, c3, OUT, M);
}